// Round 1
// baseline (2347.179 us; speedup 1.0000x reference)
//
#include <hip/hip_runtime.h>
#include <hip/hip_bf16.h>
#include <cstdint>
#include <cstddef>

// Problem dims (fixed)
#define TSTEPS 128
#define BATCH  64
#define DDIM   1024
#define HDIM   1024
#define HADIM  128
#define VOCAB  10000
#define MROWS  (TSTEPS * BATCH)   // 8192

typedef __attribute__((ext_vector_type(8))) short bf16x8;
typedef __attribute__((ext_vector_type(4))) float f32x4;

__device__ __forceinline__ unsigned short f2bf(float x) {
    unsigned int u = __float_as_uint(x);
    unsigned int r = (u + 0x7fffu + ((u >> 16) & 1u)) >> 16;
    return (unsigned short)r;
}

// ---------------- transpose + cast fp32 -> bf16 (W: RxC -> Wt: CxR) ----------------
__global__ __launch_bounds__(256) void transpose_cast(const float* __restrict__ W,
                                                      unsigned short* __restrict__ Wt,
                                                      int R, int C) {
    __shared__ float tile[32][33];
    int tc = blockIdx.x * 32;   // col base in W
    int tr = blockIdx.y * 32;   // row base in W
    int tid = threadIdx.x;
    for (int i = 0; i < 4; i++) {
        int idx = tid + i * 256;
        int r = idx >> 5, c = idx & 31;
        float v = 0.f;
        if (tr + r < R && tc + c < C) v = W[(size_t)(tr + r) * C + tc + c];
        tile[r][c] = v;
    }
    __syncthreads();
    for (int i = 0; i < 4; i++) {
        int idx = tid + i * 256;
        int r = idx >> 5, c = idx & 31;   // r = row of Wt (= col of W)
        if (tc + r < C && tr + c < R)
            Wt[(size_t)(tc + r) * R + tr + c] = f2bf(tile[c][r]);
    }
}

// ---------------- gather embedding rows + cast to bf16 ----------------
__global__ __launch_bounds__(256) void gather_cast(const int* __restrict__ tok,
                                                   const float* __restrict__ emb,
                                                   unsigned short* __restrict__ xb) {
    int i = blockIdx.x;               // 0..8191 (t*64+b)
    int t = tok[i];
    const float4* src = (const float4*)(emb + (size_t)t * DDIM);
    float4 v = src[threadIdx.x];
    ushort4 o;
    o.x = f2bf(v.x); o.y = f2bf(v.y); o.z = f2bf(v.z); o.w = f2bf(v.w);
    ((ushort4*)(xb + (size_t)i * DDIM))[threadIdx.x] = o;
}

__global__ __launch_bounds__(256) void zero_ushort(unsigned short* p, int n) {
    int i = blockIdx.x * 256 + threadIdx.x;
    if (i < n) p[i] = 0;
}

// ---------------- generic C = A @ Bt^T + bias, bf16 in / fp32 out ----------------
// A: MxK bf16 row-major; Bt: NxK bf16 row-major; C: MxN fp32. K multiple of 32, M multiple of 64.
__global__ __launch_bounds__(256) void gemm_bt_bias(const unsigned short* __restrict__ A,
                                                    const unsigned short* __restrict__ Bt,
                                                    const float* __restrict__ bias,
                                                    float* __restrict__ C,
                                                    int M, int N, int K) {
    __shared__ unsigned short As[64 * 40];
    __shared__ unsigned short Bs[64 * 40];
    int rowBase = blockIdx.y * 64;
    int colBase = blockIdx.x * 64;
    int tid = threadIdx.x;
    int wave = tid >> 6, lane = tid & 63;
    int wr = wave >> 1, wc = wave & 1;
    int quad = lane >> 4, lr = lane & 15;
    int ldRow = tid >> 2;            // 0..63
    int ldK = (tid & 3) * 8;         // 0,8,16,24
    bool bvalid = (colBase + ldRow) < N;
    const unsigned short* Ag = A + (size_t)(rowBase + ldRow) * K + ldK;
    const unsigned short* Bg = Bt + (size_t)(colBase + ldRow) * K + ldK;

    f32x4 acc[2][2] = {};
    for (int k0 = 0; k0 < K; k0 += 32) {
        uint4 av = *(const uint4*)(Ag + k0);
        uint4 bv = {};
        if (bvalid) bv = *(const uint4*)(Bg + k0);
        __syncthreads();
        *(uint4*)(As + ldRow * 40 + ldK) = av;
        *(uint4*)(Bs + ldRow * 40 + ldK) = bv;
        __syncthreads();
        bf16x8 a0 = *(const bf16x8*)(As + (wr * 32 + lr) * 40 + quad * 8);
        bf16x8 a1 = *(const bf16x8*)(As + (wr * 32 + 16 + lr) * 40 + quad * 8);
        bf16x8 b0 = *(const bf16x8*)(Bs + (wc * 32 + lr) * 40 + quad * 8);
        bf16x8 b1 = *(const bf16x8*)(Bs + (wc * 32 + 16 + lr) * 40 + quad * 8);
        acc[0][0] = __builtin_amdgcn_mfma_f32_16x16x32_bf16(a0, b0, acc[0][0], 0, 0, 0);
        acc[0][1] = __builtin_amdgcn_mfma_f32_16x16x32_bf16(a0, b1, acc[0][1], 0, 0, 0);
        acc[1][0] = __builtin_amdgcn_mfma_f32_16x16x32_bf16(a1, b0, acc[1][0], 0, 0, 0);
        acc[1][1] = __builtin_amdgcn_mfma_f32_16x16x32_bf16(a1, b1, acc[1][1], 0, 0, 0);
    }
    for (int mi = 0; mi < 2; mi++)
        for (int ni = 0; ni < 2; ni++) {
            int col = colBase + wc * 32 + ni * 16 + lr;
            if (col < N) {
                float b = bias[col];
                for (int r = 0; r < 4; r++) {
                    int row = rowBase + wr * 32 + mi * 16 + quad * 4 + r;
                    C[(size_t)row * N + col] = acc[mi][ni][r] + b;
                }
            }
        }
}

// ---------------- h0 recurrence + gates (fp32 exact, one WG per batch row) ----------------
__global__ __launch_bounds__(128) void h0_chain(const float* __restrict__ Xa,   // (T*B) x 128
                                                const float* __restrict__ Wah,  // 128 x 128
                                                const float* __restrict__ Wa,   // 128 x 2
                                                const float* __restrict__ ba,   // 2
                                                float2* __restrict__ ns) {      // T*B
    int b = blockIdx.x;      // batch 0..63
    int j = threadIdx.x;     // 0..127
    __shared__ float WahS[HADIM * HADIM];
    __shared__ float h0s[HADIM];
    __shared__ float red[4];
    for (int i = j; i < HADIM * HADIM; i += 128) WahS[i] = Wah[i];
    h0s[j] = 0.f;
    float wa0 = Wa[j * 2 + 0], wa1 = Wa[j * 2 + 1];
    float ba0 = ba[0], ba1 = ba[1];
    __syncthreads();
    for (int t = 0; t < TSTEPS; t++) {
        float acc = Xa[((size_t)t * BATCH + b) * HADIM + j];
        for (int k = 0; k < HADIM; k++) acc += h0s[k] * WahS[k * HADIM + j];
        float h0n = tanhf(acc);
        float p0 = h0n * wa0, p1 = h0n * wa1;
        for (int off = 32; off > 0; off >>= 1) {
            p0 += __shfl_down(p0, off);
            p1 += __shfl_down(p1, off);
        }
        int wv = j >> 6;
        if ((j & 63) == 0) { red[wv * 2 + 0] = p0; red[wv * 2 + 1] = p1; }
        __syncthreads();
        float n = 1.f / (1.f + __expf(-(red[0] + red[2] + ba0)));
        float s = 1.f / (1.f + __expf(-(red[1] + red[3] + ba1)));
        if (j == 0) ns[t * BATCH + b] = make_float2(n, s);
        h0s[j] = h0n;
        __syncthreads();
    }
}

// ---------------- one recurrence step: h1n = gate(Xi_t + h1 @ Whh) ----------------
// grid 256 = 4 row-groups x 64 col-groups; block = 1 wave; 16x16 C tile; K=1024, BK=64, 1-deep prefetch
__global__ __launch_bounds__(64) void rnn_step(const unsigned short* __restrict__ Aprev, // 64x1024 bf16
                                               const unsigned short* __restrict__ WhhT,  // 1024x1024 bf16
                                               const float* __restrict__ Xi_t,           // 64x1024 fp32
                                               const float2* __restrict__ ns_t,          // 64
                                               unsigned short* __restrict__ hs_t,        // 64x1024 bf16
                                               float* __restrict__ h1f) {                // 64x1024 fp32
    __shared__ unsigned short As[16 * 72];
    __shared__ unsigned short Bs[16 * 72];
    int rg = blockIdx.x & 3;
    int cg = blockIdx.x >> 2;
    int lane = threadIdx.x;
    int quad = lane >> 4, lr = lane & 15;
    int ldRow = lane >> 2;           // 0..15
    int ldK = (lane & 3) * 16;       // 0,16,32,48
    const unsigned short* Ag = Aprev + (size_t)(rg * 16 + ldRow) * HDIM + ldK;
    const unsigned short* Bg = WhhT + (size_t)(cg * 16 + ldRow) * HDIM + ldK;

    f32x4 acc = {};
    uint4 a0 = *(const uint4*)(Ag);
    uint4 a1 = *(const uint4*)(Ag + 8);
    uint4 b0 = *(const uint4*)(Bg);
    uint4 b1 = *(const uint4*)(Bg + 8);
    for (int k0 = 0; k0 < HDIM; k0 += 64) {
        __syncthreads();
        *(uint4*)(As + ldRow * 72 + ldK) = a0;
        *(uint4*)(As + ldRow * 72 + ldK + 8) = a1;
        *(uint4*)(Bs + ldRow * 72 + ldK) = b0;
        *(uint4*)(Bs + ldRow * 72 + ldK + 8) = b1;
        __syncthreads();
        if (k0 + 64 < HDIM) {
            a0 = *(const uint4*)(Ag + k0 + 64);
            a1 = *(const uint4*)(Ag + k0 + 72);
            b0 = *(const uint4*)(Bg + k0 + 64);
            b1 = *(const uint4*)(Bg + k0 + 72);
        }
        bf16x8 af0 = *(const bf16x8*)(As + lr * 72 + quad * 8);
        bf16x8 bf0 = *(const bf16x8*)(Bs + lr * 72 + quad * 8);
        bf16x8 af1 = *(const bf16x8*)(As + lr * 72 + 32 + quad * 8);
        bf16x8 bf1 = *(const bf16x8*)(Bs + lr * 72 + 32 + quad * 8);
        acc = __builtin_amdgcn_mfma_f32_16x16x32_bf16(af0, bf0, acc, 0, 0, 0);
        acc = __builtin_amdgcn_mfma_f32_16x16x32_bf16(af1, bf1, acc, 0, 0, 0);
    }
    int col = cg * 16 + lr;
    for (int r = 0; r < 4; r++) {
        int brow = rg * 16 + quad * 4 + r;
        float2 g = ns_t[brow];
        float pre = acc[r] + Xi_t[(size_t)brow * HDIM + col];
        float z = g.x * pre;
        float th = tanhf(z);
        float sg = 1.f / (1.f + __expf(-z));
        float h1n = (1.f - g.y) * th + g.y * sg;
        hs_t[(size_t)brow * HDIM + col] = f2bf(h1n);
        h1f[(size_t)brow * HDIM + col] = h1n;
    }
}

extern "C" void kernel_launch(void* const* d_in, const int* in_sizes, int n_in,
                              void* d_out, int out_size, void* d_ws, size_t ws_size,
                              hipStream_t stream) {
    const int*   tokens = (const int*)d_in[0];
    const float* emb    = (const float*)d_in[1];
    const float* Wax    = (const float*)d_in[2];
    const float* Wah    = (const float*)d_in[3];
    const float* bah    = (const float*)d_in[4];
    const float* Wa     = (const float*)d_in[5];
    const float* ba     = (const float*)d_in[6];
    const float* Wih    = (const float*)d_in[7];
    const float* Whh    = (const float*)d_in[8];
    const float* bh     = (const float*)d_in[9];
    const float* Wd     = (const float*)d_in[10];
    const float* bd     = (const float*)d_in[11];
    float* out = (float*)d_out;

    char* ws = (char*)d_ws;
    size_t off = 0;
    auto alloc = [&](size_t bytes) -> void* {
        void* p = ws + off;
        off += (bytes + 255) & ~(size_t)255;
        return p;
    };
    unsigned short* WihT = (unsigned short*)alloc((size_t)HDIM * DDIM * 2);      // 2 MB
    unsigned short* WaxT = (unsigned short*)alloc((size_t)HADIM * DDIM * 2);     // 256 KB
    unsigned short* WhhT = (unsigned short*)alloc((size_t)HDIM * HDIM * 2);      // 2 MB
    unsigned short* WdT  = (unsigned short*)alloc((size_t)VOCAB * HDIM * 2);     // ~20 MB
    unsigned short* xb   = (unsigned short*)alloc((size_t)MROWS * DDIM * 2);     // 16 MB
    float*          Xi   = (float*)alloc((size_t)MROWS * HDIM * 4);              // 32 MB
    float*          Xa   = (float*)alloc((size_t)MROWS * HADIM * 4);             // 4 MB
    unsigned short* hs   = (unsigned short*)alloc((size_t)MROWS * HDIM * 2);     // 16 MB
    float2*         ns   = (float2*)alloc((size_t)TSTEPS * BATCH * 8);           // 64 KB
    unsigned short* zerosA = (unsigned short*)alloc((size_t)BATCH * HDIM * 2);   // 128 KB
    float*          h1scr  = (float*)alloc((size_t)BATCH * HDIM * 4);            // 256 KB

    // 1. weight transposes (fp32 -> bf16, B^T layout for GEMMs)
    transpose_cast<<<dim3(32, 32), 256, 0, stream>>>(Wih, WihT, DDIM, HDIM);
    transpose_cast<<<dim3(4, 32), 256, 0, stream>>>(Wax, WaxT, DDIM, HADIM);
    transpose_cast<<<dim3(32, 32), 256, 0, stream>>>(Whh, WhhT, HDIM, HDIM);
    transpose_cast<<<dim3(313, 32), 256, 0, stream>>>(Wd, WdT, HDIM, VOCAB);
    // 2. gather x = emb[tokens] -> bf16
    gather_cast<<<MROWS, 256, 0, stream>>>(tokens, emb, xb);
    zero_ushort<<<(BATCH * HDIM + 255) / 256, 256, 0, stream>>>(zerosA, BATCH * HDIM);
    // 3. Xi = x @ Wih + bh ; Xa = x @ Wax + bah
    gemm_bt_bias<<<dim3(HDIM / 64, MROWS / 64), 256, 0, stream>>>(xb, WihT, bh, Xi, MROWS, HDIM, DDIM);
    gemm_bt_bias<<<dim3(HADIM / 64, MROWS / 64), 256, 0, stream>>>(xb, WaxT, bah, Xa, MROWS, HADIM, DDIM);
    // 4. h0 chain + gates (all timesteps)
    h0_chain<<<BATCH, 128, 0, stream>>>(Xa, Wah, Wa, ba, ns);
    // 5. h1 recurrence, one launch per step
    for (int t = 0; t < TSTEPS; t++) {
        const unsigned short* Ap = (t == 0) ? zerosA : hs + (size_t)(t - 1) * BATCH * HDIM;
        float* h1f = (t == TSTEPS - 1) ? (out + (size_t)MROWS * VOCAB) : h1scr;
        rnn_step<<<256, 64, 0, stream>>>(Ap, WhhT, Xi + (size_t)t * BATCH * HDIM,
                                         ns + t * BATCH, hs + (size_t)t * BATCH * HDIM, h1f);
    }
    // 6. decoded = hs @ Wd + bd
    gemm_bt_bias<<<dim3((VOCAB + 63) / 64, MROWS / 64), 256, 0, stream>>>(hs, WdT, bd, out, MROWS, VOCAB, HDIM);
}